// Round 15
// baseline (456.014 us; speedup 1.0000x reference)
//
#include <hip/hip_runtime.h>
#include <hip/hip_bf16.h>
#include <math.h>

#define CC 256
#define CQn 32
#define HH 64
#define WW 64
#define NN 4096
#define EPSF 1e-5f

typedef __hip_bfloat16 bf16;

typedef __attribute__((ext_vector_type(8))) short bf16x8v;
typedef __attribute__((ext_vector_type(4))) float f32x4v;

__device__ __forceinline__ float b2f(bf16 v) { return __bfloat162float(v); }
__device__ __forceinline__ bf16 f2b(float v) { return __float2bfloat16(v); }

template<typename T> __device__ __forceinline__ float ldf(const T* p, size_t i);
template<> __device__ __forceinline__ float ldf<float>(const float* p, size_t i) { return p[i]; }
template<> __device__ __forceinline__ float ldf<bf16>(const bf16* p, size_t i)  { return b2f(p[i]); }

__device__ __forceinline__ void stf(float* p, size_t i, float v) { p[i] = v; }
__device__ __forceinline__ void stf(bf16* p, size_t i, float v)  { p[i] = f2b(v); }

// ---------------- K0: dtype detector ----------------
// flag: 0 = data is bf16, 1 = data is f32.
__global__ __launch_bounds__(256)
void detect_kernel(const unsigned short* __restrict__ x1, int* __restrict__ flag)
{
    __shared__ int bad;
    if (threadIdx.x == 0) bad = 0;
    __syncthreads();
    int mybad = 0;
    for (int i = threadIdx.x; i < 16384; i += 256) {
        unsigned short u = x1[i];
        if ((u & 0x7F80u) == 0x7F80u) mybad = 1;
    }
    if (mybad) atomicOr(&bad, 1);
    __syncthreads();
    if (threadIdx.x == 0) *flag = bad ? 1 : 0;
}

// ---------------- bf16 path prep 1: x [256][4096] -> xT [4096][256] ----------------
__global__ __launch_bounds__(256)
void transpose_kernel(const int* __restrict__ dflag,
                      const bf16* __restrict__ x, bf16* __restrict__ xT)
{
    if (*dflag != 0) return;
    const int ci0 = blockIdx.x * 64;   // gridDim.x = 4
    const int p0  = blockIdx.y * 64;   // gridDim.y = 64
    const int t = threadIdx.x;
    const int r0 = t >> 3;             // 0..31
    const int ch = t & 7;              // 8 chunks of 8 bf16

    __shared__ bf16 tile[64][72];

    #pragma unroll
    for (int pass = 0; pass < 2; ++pass) {
        int r = pass * 32 + r0;
        uint4 v = *(const uint4*)(x + (size_t)(ci0 + r) * NN + p0 + ch * 8);
        *(uint4*)&tile[r][ch * 8] = v;
    }
    __syncthreads();
    #pragma unroll
    for (int pass = 0; pass < 2; ++pass) {
        int p = pass * 32 + r0;
        bf16 tmp[8];
        #pragma unroll
        for (int j = 0; j < 8; ++j) tmp[j] = tile[ch * 8 + j][p];
        *(uint4*)(xT + (size_t)(p0 + p) * CC + ci0 + ch * 8) = *(const uint4*)tmp;
    }
}

// ---------------- bf16 path prep 2: weights -> Wr[kk][m][ci], m = 2*o + isY ----------------
__global__ __launch_bounds__(256)
void packw_kernel(const int* __restrict__ dflag,
                  const bf16* __restrict__ wx, const bf16* __restrict__ wy,
                  bf16* __restrict__ Wr)
{
    if (*dflag != 0) return;
    const int lin = blockIdx.x * 256 + threadIdx.x;
    const int ci4 = lin & 63;
    const int m   = (lin >> 6) & 511;
    const int kk  = lin >> 15;                         // 0..8
    const int o   = m >> 1;
    const bf16* src = (m & 1) ? wy : wx;
    bf16 tmp[4];
    #pragma unroll
    for (int j = 0; j < 4; ++j)
        tmp[j] = src[(size_t)o * 2304 + (ci4 * 4 + j) * 9 + kk];
    *(uint2*)(Wr + ((size_t)kk * 512 + m) * CC + ci4 * 4) = *(const uint2*)tmp;
}

// ---------------- K1 (bf16): Sobel as implicit-GEMM MFMA ----------------
__global__ __launch_bounds__(256)
void sobel_mfma_kernel(const int* __restrict__ dflag,
                       const bf16* __restrict__ xT,
                       const bf16* __restrict__ Wr,
                       const bf16* __restrict__ bnx,
                       const bf16* __restrict__ bny,
                       bf16* __restrict__ xf)
{
    if (*dflag != 0) return;
    const int mt = blockIdx.x;      // 0..7
    const int y  = blockIdx.y;      // 0..63
    const int tid = threadIdx.x;
    const int w = tid >> 6, lane = tid & 63;
    const int wm = (w >> 1) * 32, wn = (w & 1) * 32;
    const int lr = lane & 15, q = lane >> 4;

    __shared__ char smem[18432];
    bf16* Asm = (bf16*)smem;                 // [64][40]
    bf16* Bsm = Asm + 64 * 40;               // [64][40]
    float* eb = (float*)smem;                // [64][72] epilogue reuse

    f32x4v acc[2][2];
    #pragma unroll
    for (int i = 0; i < 2; ++i)
        #pragma unroll
        for (int j = 0; j < 2; ++j) acc[i][j] = (f32x4v){0.f, 0.f, 0.f, 0.f};

    const int r = tid >> 2, ch = tid & 3;
    const bf16* Arow = Wr + (size_t)(mt * 64 + r) * CC + ch * 8;

    for (int kk = 0; kk < 9; ++kk) {
        const int dy = kk / 3 - 1, dx = kk - (kk / 3) * 3 - 1;
        const int ys = y + dy, xs = r + dx;
        const bool ok = (ys >= 0) && (ys < HH) && (xs >= 0) && (xs < WW);
        const bf16* Brow = xT + (size_t)(ys * WW + xs) * CC + ch * 8;
        const bf16* Ak = Arow + (size_t)kk * (512 * CC);
        for (int c0 = 0; c0 < CC; c0 += 32) {
            uint4 av = *(const uint4*)(Ak + c0);
            uint4 bv = make_uint4(0u, 0u, 0u, 0u);
            if (ok) bv = *(const uint4*)(Brow + c0);
            __syncthreads();
            *(uint4*)&Asm[r * 40 + ch * 8] = av;
            *(uint4*)&Bsm[r * 40 + ch * 8] = bv;
            __syncthreads();
            bf16x8v a0 = *(const bf16x8v*)&Asm[(wm + lr) * 40 + q * 8];
            bf16x8v a1 = *(const bf16x8v*)&Asm[(wm + 16 + lr) * 40 + q * 8];
            bf16x8v b0 = *(const bf16x8v*)&Bsm[(wn + lr) * 40 + q * 8];
            bf16x8v b1 = *(const bf16x8v*)&Bsm[(wn + 16 + lr) * 40 + q * 8];
            acc[0][0] = __builtin_amdgcn_mfma_f32_16x16x32_bf16(a0, b0, acc[0][0], 0, 0, 0);
            acc[0][1] = __builtin_amdgcn_mfma_f32_16x16x32_bf16(a0, b1, acc[0][1], 0, 0, 0);
            acc[1][0] = __builtin_amdgcn_mfma_f32_16x16x32_bf16(a1, b0, acc[1][0], 0, 0, 0);
            acc[1][1] = __builtin_amdgcn_mfma_f32_16x16x32_bf16(a1, b1, acc[1][1], 0, 0, 0);
        }
    }

    __syncthreads();
    #pragma unroll
    for (int fm = 0; fm < 2; ++fm)
        #pragma unroll
        for (int fn = 0; fn < 2; ++fn)
            #pragma unroll
            for (int reg = 0; reg < 4; ++reg)
                eb[(wm + fm * 16 + q * 4 + reg) * 72 + (wn + fn * 16 + lr)] = acc[fm][fn][reg];
    __syncthreads();
    {
        const int oc_l = tid >> 3, nch = tid & 7;
        const int oc = mt * 32 + oc_l;
        const float invx = b2f(bnx[oc]) * rsqrtf(b2f(bnx[3 * CC + oc]) + EPSF);
        const float bx   = b2f(bnx[CC + oc]);
        const float mx   = b2f(bnx[2 * CC + oc]);
        const float invy = b2f(bny[oc]) * rsqrtf(b2f(bny[3 * CC + oc]) + EPSF);
        const float by   = b2f(bny[CC + oc]);
        const float my   = b2f(bny[2 * CC + oc]);
        bf16 outv[8];
        #pragma unroll
        for (int j = 0; j < 8; ++j) {
            float gxv = eb[(2 * oc_l) * 72 + nch * 8 + j];
            float gyv = eb[(2 * oc_l + 1) * 72 + nch * 8 + j];
            float gxn = (gxv - mx) * invx + bx;
            float gyn = (gyv - my) * invy + by;
            outv[j] = f2b(sqrtf(gxn * gxn + gyn * gyn));
        }
        *(uint4*)(xf + (size_t)oc * NN + y * WW + nch * 8) = *(const uint4*)outv;
    }
}

// ---------------- f32 path prep: x f32 [256][4096] -> xT_hi + xT_lo bf16 [4096][256] ----------------
__global__ __launch_bounds__(256)
void transpose_split_kernel(const int* __restrict__ dflag,
                            const float* __restrict__ x,
                            bf16* __restrict__ xT_hi, bf16* __restrict__ xT_lo)
{
    if (*dflag != 1) return;
    const int ci0 = blockIdx.x * 64;   // 4
    const int p0  = blockIdx.y * 64;   // 64
    const int t = threadIdx.x;
    const int r = t >> 2, ch = t & 3;

    __shared__ float tile[64][76];

    {
        const float* src = x + (size_t)(ci0 + r) * NN + p0 + ch * 16;
        #pragma unroll
        for (int i = 0; i < 4; ++i) {
            float4 v = *(const float4*)(src + i * 4);
            *(float4*)&tile[r][ch * 16 + i * 4] = v;
        }
    }
    __syncthreads();
    {
        bf16 hi[16], lo[16];
        #pragma unroll
        for (int j = 0; j < 16; ++j) {
            float v = tile[ch * 16 + j][r];
            bf16 h = f2b(v);
            hi[j] = h;
            lo[j] = f2b(v - b2f(h));
        }
        size_t base = (size_t)(p0 + r) * CC + ci0 + ch * 16;
        *(uint4*)(xT_hi + base)     = ((const uint4*)hi)[0];
        *(uint4*)(xT_hi + base + 8) = ((const uint4*)hi)[1];
        *(uint4*)(xT_lo + base)     = ((const uint4*)lo)[0];
        *(uint4*)(xT_lo + base + 8) = ((const uint4*)lo)[1];
    }
}

// ---------------- K1 (f32): Sobel as split-precision implicit-GEMM MFMA ----------------
// v2: M-split 2x for occupancy — tile 32M x 64N, grid (16, 64) = 1024 blocks.
__global__ __launch_bounds__(256)
void sobel_mfma_f32_kernel(const int* __restrict__ dflag,
                           const bf16* __restrict__ xTh,
                           const bf16* __restrict__ xTl,
                           const float* __restrict__ wx,
                           const float* __restrict__ wy,
                           const float* __restrict__ bnx,
                           const float* __restrict__ bny,
                           bf16* __restrict__ xf)
{
    if (*dflag != 1) return;
    const int mt = blockIdx.x;      // 0..15 (32 M-rows each; m = 2*oc + isY, 16 oc/block)
    const int y  = blockIdx.y;      // 0..63
    const int tid = threadIdx.x;
    const int w = tid >> 6, lane = tid & 63;
    const int wm = (w >> 1) * 16, wn = (w & 1) * 32;
    const int lr = lane & 15, q = lane >> 4;

    __shared__ char smem[16384];
    bf16* Ah = (bf16*)smem;          // [32][40] (2560 B)
    bf16* Al = Ah + 1280;            // [32][40]
    bf16* Bh = Al + 1280;            // [66][40] halo rows 0,65 zero
    bf16* Bl = Bh + 2640;            // [66][40]
    float* eb = (float*)smem;        // [32][72] epilogue reuse (9216 B)

    f32x4v acc[2];
    acc[0] = (f32x4v){0.f, 0.f, 0.f, 0.f};
    acc[1] = (f32x4v){0.f, 0.f, 0.f, 0.f};

    const int r = tid >> 2, ch = tid & 3;     // B staging row (0..63)
    const bool aAct = tid < 128;              // A rows 0..31
    const int o = mt * 16 + (r >> 1);         // valid when aAct
    const float* wbase = aAct ? (((r & 1) ? wy : wx) + (size_t)o * 2304) : wx;

    if (tid < 40) {
        Bh[tid] = f2b(0.f);           Bl[tid] = f2b(0.f);
        Bh[65 * 40 + tid] = f2b(0.f); Bl[65 * 40 + tid] = f2b(0.f);
    }

    for (int c0i = 0; c0i < 8; ++c0i) {
        const int c0 = c0i * 32;
        for (int dy = 0; dy < 3; ++dy) {
            const int ys = y + dy - 1;
            float wv[8][3];
            if (aAct) {
                const float* wb = wbase + (size_t)(c0 + ch * 8) * 9 + dy * 3;
                #pragma unroll
                for (int j = 0; j < 8; ++j)
                    #pragma unroll
                    for (int d = 0; d < 3; ++d)
                        wv[j][d] = wb[j * 9 + d];
            }
            uint4 bh = make_uint4(0u, 0u, 0u, 0u), bl = make_uint4(0u, 0u, 0u, 0u);
            if (ys >= 0 && ys < HH) {
                size_t bidx = (size_t)(ys * WW + r) * CC + c0 + ch * 8;
                bh = *(const uint4*)(xTh + bidx);
                bl = *(const uint4*)(xTl + bidx);
            }
            #pragma unroll
            for (int d = 0; d < 3; ++d) {
                __syncthreads();
                if (aAct) {
                    bf16 ah8[8], al8[8];
                    #pragma unroll
                    for (int j = 0; j < 8; ++j) {
                        float v = wv[j][d];
                        bf16 h = f2b(v);
                        ah8[j] = h;
                        al8[j] = f2b(v - b2f(h));
                    }
                    *(uint4*)&Ah[r * 40 + ch * 8] = *(const uint4*)ah8;
                    *(uint4*)&Al[r * 40 + ch * 8] = *(const uint4*)al8;
                }
                if (d == 0) {
                    *(uint4*)&Bh[(r + 1) * 40 + ch * 8] = bh;
                    *(uint4*)&Bl[(r + 1) * 40 + ch * 8] = bl;
                }
                __syncthreads();
                bf16x8v ah0 = *(const bf16x8v*)&Ah[(wm + lr) * 40 + q * 8];
                bf16x8v al0 = *(const bf16x8v*)&Al[(wm + lr) * 40 + q * 8];
                const int b0r = wn + lr + d, b1r = wn + 16 + lr + d;
                bf16x8v bh0 = *(const bf16x8v*)&Bh[b0r * 40 + q * 8];
                bf16x8v bh1 = *(const bf16x8v*)&Bh[b1r * 40 + q * 8];
                bf16x8v bl0 = *(const bf16x8v*)&Bl[b0r * 40 + q * 8];
                bf16x8v bl1 = *(const bf16x8v*)&Bl[b1r * 40 + q * 8];
                acc[0] = __builtin_amdgcn_mfma_f32_16x16x32_bf16(ah0, bh0, acc[0], 0, 0, 0);
                acc[0] = __builtin_amdgcn_mfma_f32_16x16x32_bf16(ah0, bl0, acc[0], 0, 0, 0);
                acc[0] = __builtin_amdgcn_mfma_f32_16x16x32_bf16(al0, bh0, acc[0], 0, 0, 0);
                acc[1] = __builtin_amdgcn_mfma_f32_16x16x32_bf16(ah0, bh1, acc[1], 0, 0, 0);
                acc[1] = __builtin_amdgcn_mfma_f32_16x16x32_bf16(ah0, bl1, acc[1], 0, 0, 0);
                acc[1] = __builtin_amdgcn_mfma_f32_16x16x32_bf16(al0, bh1, acc[1], 0, 0, 0);
            }
        }
    }

    __syncthreads();
    #pragma unroll
    for (int fn = 0; fn < 2; ++fn)
        #pragma unroll
        for (int reg = 0; reg < 4; ++reg)
            eb[(wm + q * 4 + reg) * 72 + (wn + fn * 16 + lr)] = acc[fn][reg];
    __syncthreads();
    if (tid < 128) {
        const int oc_l = tid >> 3, nch = tid & 7;
        const int oc = mt * 16 + oc_l;
        const float invx = bnx[oc] * rsqrtf(bnx[3 * CC + oc] + EPSF);
        const float bx   = bnx[CC + oc];
        const float mx   = bnx[2 * CC + oc];
        const float invy = bny[oc] * rsqrtf(bny[3 * CC + oc] + EPSF);
        const float by   = bny[CC + oc];
        const float my   = bny[2 * CC + oc];
        bf16 outv[8];
        #pragma unroll
        for (int j = 0; j < 8; ++j) {
            float gxv = eb[(2 * oc_l) * 72 + nch * 8 + j];
            float gyv = eb[(2 * oc_l + 1) * 72 + nch * 8 + j];
            float gxn = (gxv - mx) * invx + bx;
            float gyn = (gyv - my) * invy + by;
            outv[j] = f2b(sqrtf(gxn * gxn + gyn * gyn));
        }
        *(uint4*)(xf + (size_t)oc * NN + y * WW + nch * 8) = *(const uint4*)outv;
    }
}

// ---------------- K2: 1x1 convs -> MFMA-ready q/k/v operands ----------------
// v3: flat 640-unit all-active grid, plain c-loop (no forced unroll).
template<typename T>
__global__ __launch_bounds__(256)
void qkv_kernel(const int* __restrict__ dflag, int want,
                const T* __restrict__ x1, const T* __restrict__ x2,
                const bf16* __restrict__ xf1, const bf16* __restrict__ xf2,
                const T* __restrict__ q1w, const T* __restrict__ q1b,
                const T* __restrict__ k1w, const T* __restrict__ k1b,
                const T* __restrict__ v1w, const T* __restrict__ v1b,
                const T* __restrict__ q2w, const T* __restrict__ q2b,
                const T* __restrict__ k2w, const T* __restrict__ k2b,
                const T* __restrict__ v2w, const T* __restrict__ v2b,
                bf16* __restrict__ qc1, bf16* __restrict__ kc1, bf16* __restrict__ v1t,
                bf16* __restrict__ qc2, bf16* __restrict__ kc2, bf16* __restrict__ v2t)
{
    if (*dflag != want) return;
    const int unit = blockIdx.x;
    int z, o0, n0;
    if (unit < 128) {
        const int s = unit >> 5;             // 0..3
        const int rem = unit & 31;
        o0 = (rem >> 4) * 16;                // 0 or 16
        n0 = (rem & 15) * 256;
        z = (s == 0) ? 0 : (s == 1) ? 1 : (s == 2) ? 3 : 4;
    } else {
        const int u = unit - 128;            // 0..511
        const int rem = u & 255;
        o0 = (rem >> 4) * 16;                // 0..240
        n0 = (rem & 15) * 256;
        z = (u >> 8) ? 5 : 2;
    }

    const T* Wb; const T* bias;
    const T* Xt = nullptr; const bf16* Xb = nullptr;
    bf16* outQ = nullptr; bf16* outK = nullptr; bf16* outV = nullptr;
    switch (z) {
        case 0:  Wb = q1w; bias = q1b; Xt = x1;  outQ = qc1; break;
        case 1:  Wb = k1w; bias = k1b; Xb = xf2; outK = kc1; break;
        case 2:  Wb = v1w; bias = v1b; Xb = xf2; outV = v1t; break;
        case 3:  Wb = q2w; bias = q2b; Xt = x2;  outQ = qc2; break;
        case 4:  Wb = k2w; bias = k2b; Xb = xf1; outK = kc2; break;
        default: Wb = v2w; bias = v2b; Xb = xf1; outV = v2t; break;
    }
    const int tid = threadIdx.x;

    __shared__ float lw[16 * 256];        // lw[o][c]
    for (int idx = tid; idx < 16 * 256; idx += 256)
        lw[idx] = ldf(Wb, (size_t)o0 * CC + idx);
    __syncthreads();

    const int n = n0 + tid;

    float acc[16];
    #pragma unroll
    for (int o = 0; o < 16; ++o) acc[o] = 0.f;

    const float4* lw4 = (const float4*)lw;
    for (int c4 = 0; c4 < 64; ++c4) {
        float xa[4];
        #pragma unroll
        for (int k = 0; k < 4; ++k) {
            size_t ia = (size_t)(c4 * 4 + k) * NN + n;
            xa[k] = Xt ? ldf(Xt, ia) : b2f(Xb[ia]);
        }
        #pragma unroll
        for (int o = 0; o < 16; ++o) {
            float4 w4 = lw4[o * 64 + c4];
            acc[o] = fmaf(w4.x, xa[0], fmaf(w4.y, xa[1], fmaf(w4.z, xa[2], fmaf(w4.w, xa[3], acc[o]))));
        }
    }
    #pragma unroll
    for (int o = 0; o < 16; ++o) acc[o] += ldf(bias, o0 + o);

    if (outV) {
        #pragma unroll
        for (int o = 0; o < 16; ++o)
            outV[((size_t)(n >> 6) * CC + (o0 + o)) * 64 + (n & 63)] = f2b(acc[o]);
    } else {
        bf16 hi[16], lo[16];
        #pragma unroll
        for (int o = 0; o < 16; ++o) {
            float v = acc[o];
            bf16 h = f2b(v);
            hi[o] = h;
            lo[o] = f2b(v - b2f(h));
        }
        if (outQ) {
            bf16* row = outQ + (size_t)n * 64 + o0;      // hi at [o0, o0+16)
            ((uint4*)row)[0] = ((const uint4*)hi)[0];
            ((uint4*)row)[1] = ((const uint4*)hi)[1];
            bf16* rowl = row + 32;                       // lo at [32+o0, ...)
            ((uint4*)rowl)[0] = ((const uint4*)lo)[0];
            ((uint4*)rowl)[1] = ((const uint4*)lo)[1];
        } else {
            bf16* row = outK + (size_t)n * 96 + o0;
            ((uint4*)row)[0] = ((const uint4*)hi)[0];
            ((uint4*)row)[1] = ((const uint4*)hi)[1];
            bf16* row2 = row + 32;
            ((uint4*)row2)[0] = ((const uint4*)hi)[0];
            ((uint4*)row2)[1] = ((const uint4*)hi)[1];
            bf16* row3 = row + 64;
            ((uint4*)row3)[0] = ((const uint4*)lo)[0];
            ((uint4*)row3)[1] = ((const uint4*)lo)[1];
        }
    }
}

// ---------------- K3: MFMA flash attention (v10: channel-split blocks) ----------------
// 1024 blocks: att = b>>9, i0 = ((b>>1)&255)*16, half = b&1 -> 4 blk/CU.
// Each block: full QK^T + softmax over all keys (cheap since v9: 3 MFMA +
// 4 exp/thread/tile; l is block-local, no cross-block combine) but only 128
// of 256 V channels: half the V staging, half the PV MFMAs, half the
// accumulators/epilogue. LDS 36.5 KB: Kc [64][128] swz + Vt [128][64] swz +
// Ph/Pl [16][72]. K staging + QK^T duplicated across the half-pair (L2-hot).
__device__ __forceinline__ int vswz(int chunk, int row) { return (chunk ^ (row & 7)) * 8; }

template<typename T>
__global__ __launch_bounds__(256)
void attend_mfma_kernel(const int* __restrict__ dflag, int want,
                        const bf16* __restrict__ qc1, const bf16* __restrict__ kc1,
                        const bf16* __restrict__ v1, const T* __restrict__ x1,
                        const T* __restrict__ g1,
                        const bf16* __restrict__ qc2, const bf16* __restrict__ kc2,
                        const bf16* __restrict__ v2, const T* __restrict__ x2,
                        const T* __restrict__ g2,
                        T* __restrict__ out)
{
    if (*dflag != want) return;
    const int att = blockIdx.x >> 9;
    const int i0 = ((blockIdx.x >> 1) & 255) * 16;
    const int half = blockIdx.x & 1;          // which 128 V channels
    const bf16* qc = att ? qc2 : qc1;
    const bf16* kc = att ? kc2 : kc1;
    const bf16* vt = att ? v2 : v1;
    const T* xq = att ? x2 : x1;
    const T* gp = att ? g2 : g1;
    T* o = out + (size_t)att * CC * NN;

    const int tid = threadIdx.x;
    const int w = tid >> 6, lane = tid & 63;
    const int lr = lane & 15, g = lane >> 4;

    __shared__ __align__(16) bf16 lds[18688];   // 37376 B
    bf16* Kc = lds;                  // [64][128] swizzled (16384 B)
    bf16* Vt = lds + 8192;           // [128][64] swizzled (16384 B)
    bf16* Ph = lds + 16384;          // [16][72]
    bf16* Pl = lds + 17536;          // [16][72]

    // Q fragments: row q = i0+lr, k-chunk g*8 (A-frag layout)
    const bf16* qrow = qc + (size_t)(i0 + lr) * 64 + g * 8;
    bf16x8v qh = *(const bf16x8v*)(qrow);
    bf16x8v ql = *(const bf16x8v*)(qrow + 32);

    float l_r[4];
    #pragma unroll
    for (int r = 0; r < 4; ++r) l_r[r] = 0.f;
    f32x4v oacc[2];
    oacc[0] = (f32x4v){0.f, 0.f, 0.f, 0.f};
    oacc[1] = (f32x4v){0.f, 0.f, 0.f, 0.f};

    for (int jt = 0; jt < 64; ++jt) {
        const int j0 = jt * 64;
        __syncthreads();                      // prior tile's LDS reads done
        // stage K tile: 768 uint4 cooperatively, XOR-swizzled rows
        #pragma unroll
        for (int s = 0; s < 3; ++s) {
            int idx = tid + s * 256;
            int row = idx / 12, cq = idx - row * 12;
            uint4 u = *(const uint4*)(kc + (size_t)(j0 + row) * 96 + cq * 8);
            *(uint4*)&Kc[row * 128 + vswz(cq, row)] = u;
        }
        // stage V tile: this block's 128 channels (contiguous 16 KB, coalesced)
        {
            const bf16* src = vt + ((size_t)jt * (CC * 64)) + (size_t)half * (128 * 64);
            #pragma unroll
            for (int i = 0; i < 4; ++i) {
                const int idx = i * 256 + tid;       // 16B-chunk index (1024 total)
                const int c = idx >> 3, chk = idx & 7;
                *(uint4*)&Vt[c * 64 + vswz(chk, c)] =
                    *(const uint4*)(src + (size_t)idx * 8);
            }
        }
        __syncthreads();                      // Kc + Vt ready

        // ---- QK^T: this wave's key quarter only (keys w*16 + lr) ----
        f32x4v e;
        {
            const bf16* kr = Kc + (w * 16 + lr) * 128;
            bf16x8v b0 = *(const bf16x8v*)(kr + vswz(g, lr));
            bf16x8v b1 = *(const bf16x8v*)(kr + vswz(4 + g, lr));
            bf16x8v b2 = *(const bf16x8v*)(kr + vswz(8 + g, lr));
            f32x4v z = (f32x4v){0.f, 0.f, 0.f, 0.f};
            z = __builtin_amdgcn_mfma_f32_16x16x32_bf16(qh, b0, z, 0, 0, 0);
            z = __builtin_amdgcn_mfma_f32_16x16x32_bf16(ql, b1, z, 0, 0, 0);
            z = __builtin_amdgcn_mfma_f32_16x16x32_bf16(qh, b2, z, 0, 0, 0);
            e = z;
        }
        // ---- weights: p = exp(e), partial l over this wave's quarter ----
        #pragma unroll
        for (int r = 0; r < 4; ++r) {
            float p = __expf(e[r]);
            l_r[r] += p;
            bf16 ph = f2b(p);
            Ph[(g * 4 + r) * 72 + w * 16 + lr] = ph;
            Pl[(g * 4 + r) * 72 + w * 16 + lr] = f2b(p - b2f(ph));
        }
        __syncthreads();                      // P complete (cross-wave)

        // ---- PV (this block's 128 channels; rowc = w*32 + f*16 + lr) ----
        bf16x8v pah[2], pal[2];
        #pragma unroll
        for (int ks = 0; ks < 2; ++ks) {
            pah[ks] = *(const bf16x8v*)&Ph[lr * 72 + ks * 32 + g * 8];
            pal[ks] = *(const bf16x8v*)&Pl[lr * 72 + ks * 32 + g * 8];
        }
        #pragma unroll
        for (int f = 0; f < 2; ++f) {
            const int rowc = w * 32 + f * 16 + lr;
            const bf16* vr = Vt + rowc * 64;
            #pragma unroll
            for (int ks = 0; ks < 2; ++ks) {
                bf16x8v bv = *(const bf16x8v*)(vr + vswz(ks * 4 + g, lr));
                oacc[f] = __builtin_amdgcn_mfma_f32_16x16x32_bf16(pah[ks], bv, oacc[f], 0, 0, 0);
                oacc[f] = __builtin_amdgcn_mfma_f32_16x16x32_bf16(pal[ks], bv, oacc[f], 0, 0, 0);
            }
        }
    }

    // ---- reduce l across the 16-lane group (keys within this wave's quarter) ----
    #pragma unroll
    for (int r = 0; r < 4; ++r)
        #pragma unroll
        for (int msk = 1; msk <= 8; msk <<= 1)
            l_r[r] += __shfl_xor(l_r[r], msk);

    // ---- epilogue: transpose via LDS, combine l partials, residual, store ----
    __syncthreads();
    float* ob = (float*)lds;          // [128][20] (2560 floats)
    float* lp = ob + 2560;            // [4][16] per-wave l partials
    #pragma unroll
    for (int f = 0; f < 2; ++f)
        #pragma unroll
        for (int r = 0; r < 4; ++r)
            ob[(w * 32 + f * 16 + lr) * 20 + g * 4 + r] = oacc[f][r];
    if (lr == 0) {
        #pragma unroll
        for (int r = 0; r < 4; ++r) lp[w * 16 + g * 4 + r] = l_r[r];
    }
    __syncthreads();
    {
        const float gm = ldf(gp, 0);
        const int c_l = tid & 127, qh8 = (tid >> 7) * 8;
        const int c = half * 128 + c_l;
        const size_t rowo = (size_t)c * NN + i0;
        #pragma unroll
        for (int qq = 0; qq < 8; ++qq) {
            const int q = qh8 + qq;
            float lq = (lp[q] + lp[16 + q]) + (lp[32 + q] + lp[48 + q]);
            float v = ob[c_l * 20 + q] / lq;
            float xv = ldf(xq, rowo + q);
            stf(o, rowo + q, fmaf(gm, v, xv));
        }
    }
}

extern "C" void kernel_launch(void* const* d_in, const int* in_sizes, int n_in,
                              void* d_out, int out_size, void* d_ws, size_t ws_size,
                              hipStream_t stream) {
    // workspace: 256B flag + xf1(2M) xf2(2M) + union(6.5M):
    //   sobel phase : xT/xTh(2M) Wr|xTl(2.25M/2M)
    //   post-sobel  : v1t(2M) v2t(2M) qc1(512K) kc1(768K) qc2(512K) kc2(768K)
    // total 11,010,304 B (prior session proved ws_size >= 11 MB).
    if (ws_size < (size_t)11010304) return;

    int* dflag = (int*)d_ws;
    char* base = (char*)d_ws + 256;
    bf16* xf1 = (bf16*)base;               // 2 MB
    bf16* xf2 = xf1 + 1048576;             // 2 MB
    char* ubase = (char*)(xf2 + 1048576);  // 6.5 MB union region
    bf16* xTb = (bf16*)ubase;                          // bf16 sobel
    bf16* Wrb = (bf16*)(ubase + 2 * 1024 * 1024);
    bf16* xTh = (bf16*)ubase;                          // f32 sobel
    bf16* xTl = (bf16*)(ubase + 2 * 1024 * 1024);
    bf16* v1t = (bf16*)ubase;              // [64][256][64] bf16 tile-major, 2 MB
    bf16* v2t = v1t + 1048576;             // 2 MB
    bf16* qc1 = v2t + 1048576;             // [4096][64], 512 KB
    bf16* kc1 = qc1 + 262144;              // [4096][96], 768 KB
    bf16* qc2 = kc1 + 393216;              // 512 KB
    bf16* kc2 = qc2 + 262144;              // 768 KB

    detect_kernel<<<dim3(1), 256, 0, stream>>>((const unsigned short*)d_in[0], dflag);

    // ---- bf16 pipeline (want=0) ----
    {
        typedef bf16 T;
        transpose_kernel<<<dim3(4, 64), 256, 0, stream>>>(dflag, (const T*)d_in[0], xTb);
        packw_kernel<<<dim3(1152), 256, 0, stream>>>(dflag, (const T*)d_in[2], (const T*)d_in[3], Wrb);
        sobel_mfma_kernel<<<dim3(8, 64), 256, 0, stream>>>(dflag, xTb, Wrb,
            (const T*)d_in[4], (const T*)d_in[5], xf1);
        transpose_kernel<<<dim3(4, 64), 256, 0, stream>>>(dflag, (const T*)d_in[1], xTb);
        packw_kernel<<<dim3(1152), 256, 0, stream>>>(dflag, (const T*)d_in[6], (const T*)d_in[7], Wrb);
        sobel_mfma_kernel<<<dim3(8, 64), 256, 0, stream>>>(dflag, xTb, Wrb,
            (const T*)d_in[8], (const T*)d_in[9], xf2);
        qkv_kernel<T><<<dim3(640), 256, 0, stream>>>(dflag, 0,
            (const T*)d_in[0], (const T*)d_in[1], xf1, xf2,
            (const T*)d_in[10], (const T*)d_in[11], (const T*)d_in[12], (const T*)d_in[13],
            (const T*)d_in[14], (const T*)d_in[15], (const T*)d_in[16], (const T*)d_in[17],
            (const T*)d_in[18], (const T*)d_in[19], (const T*)d_in[20], (const T*)d_in[21],
            qc1, kc1, v1t, qc2, kc2, v2t);
        attend_mfma_kernel<T><<<dim3(1024), 256, 0, stream>>>(dflag, 0,
            qc1, kc1, v1t, (const T*)d_in[0], (const T*)d_in[22],
            qc2, kc2, v2t, (const T*)d_in[1], (const T*)d_in[23],
            (T*)d_out);
    }
    // ---- f32 pipeline (want=1) ----
    {
        typedef float T;
        transpose_split_kernel<<<dim3(4, 64), 256, 0, stream>>>(dflag, (const T*)d_in[0], xTh, xTl);
        sobel_mfma_f32_kernel<<<dim3(16, 64), 256, 0, stream>>>(dflag, xTh, xTl,
            (const T*)d_in[2], (const T*)d_in[3], (const T*)d_in[4], (const T*)d_in[5], xf1);
        transpose_split_kernel<<<dim3(4, 64), 256, 0, stream>>>(dflag, (const T*)d_in[1], xTh, xTl);
        sobel_mfma_f32_kernel<<<dim3(16, 64), 256, 0, stream>>>(dflag, xTh, xTl,
            (const T*)d_in[6], (const T*)d_in[7], (const T*)d_in[8], (const T*)d_in[9], xf2);
        qkv_kernel<T><<<dim3(640), 256, 0, stream>>>(dflag, 1,
            (const T*)d_in[0], (const T*)d_in[1], xf1, xf2,
            (const T*)d_in[10], (const T*)d_in[11], (const T*)d_in[12], (const T*)d_in[13],
            (const T*)d_in[14], (const T*)d_in[15], (const T*)d_in[16], (const T*)d_in[17],
            (const T*)d_in[18], (const T*)d_in[19], (const T*)d_in[20], (const T*)d_in[21],
            qc1, kc1, v1t, qc2, kc2, v2t);
        attend_mfma_kernel<T><<<dim3(1024), 256, 0, stream>>>(dflag, 1,
            qc1, kc1, v1t, (const T*)d_in[0], (const T*)d_in[22],
            qc2, kc2, v2t, (const T*)d_in[1], (const T*)d_in[23],
            (T*)d_out);
    }
}

// Round 16
// 433.733 us; speedup vs baseline: 1.0514x; 1.0514x over previous
//
#include <hip/hip_runtime.h>
#include <hip/hip_bf16.h>
#include <math.h>

#define CC 256
#define CQn 32
#define HH 64
#define WW 64
#define NN 4096
#define EPSF 1e-5f

typedef __hip_bfloat16 bf16;

typedef __attribute__((ext_vector_type(8))) short bf16x8v;
typedef __attribute__((ext_vector_type(4))) float f32x4v;

__device__ __forceinline__ float b2f(bf16 v) { return __bfloat162float(v); }
__device__ __forceinline__ bf16 f2b(float v) { return __float2bfloat16(v); }

template<typename T> __device__ __forceinline__ float ldf(const T* p, size_t i);
template<> __device__ __forceinline__ float ldf<float>(const float* p, size_t i) { return p[i]; }
template<> __device__ __forceinline__ float ldf<bf16>(const bf16* p, size_t i)  { return b2f(p[i]); }

__device__ __forceinline__ void stf(float* p, size_t i, float v) { p[i] = v; }
__device__ __forceinline__ void stf(bf16* p, size_t i, float v)  { p[i] = f2b(v); }

// ---------------- K0: dtype detector ----------------
// flag: 0 = data is bf16, 1 = data is f32.
__global__ __launch_bounds__(256)
void detect_kernel(const unsigned short* __restrict__ x1, int* __restrict__ flag)
{
    __shared__ int bad;
    if (threadIdx.x == 0) bad = 0;
    __syncthreads();
    int mybad = 0;
    for (int i = threadIdx.x; i < 16384; i += 256) {
        unsigned short u = x1[i];
        if ((u & 0x7F80u) == 0x7F80u) mybad = 1;
    }
    if (mybad) atomicOr(&bad, 1);
    __syncthreads();
    if (threadIdx.x == 0) *flag = bad ? 1 : 0;
}

// ---------------- bf16 path prep 1: x [256][4096] -> xT [4096][256] ----------------
__global__ __launch_bounds__(256)
void transpose_kernel(const int* __restrict__ dflag,
                      const bf16* __restrict__ x, bf16* __restrict__ xT)
{
    if (*dflag != 0) return;
    const int ci0 = blockIdx.x * 64;   // gridDim.x = 4
    const int p0  = blockIdx.y * 64;   // gridDim.y = 64
    const int t = threadIdx.x;
    const int r0 = t >> 3;             // 0..31
    const int ch = t & 7;              // 8 chunks of 8 bf16

    __shared__ bf16 tile[64][72];

    #pragma unroll
    for (int pass = 0; pass < 2; ++pass) {
        int r = pass * 32 + r0;
        uint4 v = *(const uint4*)(x + (size_t)(ci0 + r) * NN + p0 + ch * 8);
        *(uint4*)&tile[r][ch * 8] = v;
    }
    __syncthreads();
    #pragma unroll
    for (int pass = 0; pass < 2; ++pass) {
        int p = pass * 32 + r0;
        bf16 tmp[8];
        #pragma unroll
        for (int j = 0; j < 8; ++j) tmp[j] = tile[ch * 8 + j][p];
        *(uint4*)(xT + (size_t)(p0 + p) * CC + ci0 + ch * 8) = *(const uint4*)tmp;
    }
}

// ---------------- bf16 path prep 2: weights -> Wr[kk][m][ci], m = 2*o + isY ----------------
__global__ __launch_bounds__(256)
void packw_kernel(const int* __restrict__ dflag,
                  const bf16* __restrict__ wx, const bf16* __restrict__ wy,
                  bf16* __restrict__ Wr)
{
    if (*dflag != 0) return;
    const int lin = blockIdx.x * 256 + threadIdx.x;
    const int ci4 = lin & 63;
    const int m   = (lin >> 6) & 511;
    const int kk  = lin >> 15;                         // 0..8
    const int o   = m >> 1;
    const bf16* src = (m & 1) ? wy : wx;
    bf16 tmp[4];
    #pragma unroll
    for (int j = 0; j < 4; ++j)
        tmp[j] = src[(size_t)o * 2304 + (ci4 * 4 + j) * 9 + kk];
    *(uint2*)(Wr + ((size_t)kk * 512 + m) * CC + ci4 * 4) = *(const uint2*)tmp;
}

// ---------------- K1 (bf16): Sobel as implicit-GEMM MFMA ----------------
__global__ __launch_bounds__(256)
void sobel_mfma_kernel(const int* __restrict__ dflag,
                       const bf16* __restrict__ xT,
                       const bf16* __restrict__ Wr,
                       const bf16* __restrict__ bnx,
                       const bf16* __restrict__ bny,
                       bf16* __restrict__ xf)
{
    if (*dflag != 0) return;
    const int mt = blockIdx.x;      // 0..7
    const int y  = blockIdx.y;      // 0..63
    const int tid = threadIdx.x;
    const int w = tid >> 6, lane = tid & 63;
    const int wm = (w >> 1) * 32, wn = (w & 1) * 32;
    const int lr = lane & 15, q = lane >> 4;

    __shared__ char smem[18432];
    bf16* Asm = (bf16*)smem;                 // [64][40]
    bf16* Bsm = Asm + 64 * 40;               // [64][40]
    float* eb = (float*)smem;                // [64][72] epilogue reuse

    f32x4v acc[2][2];
    #pragma unroll
    for (int i = 0; i < 2; ++i)
        #pragma unroll
        for (int j = 0; j < 2; ++j) acc[i][j] = (f32x4v){0.f, 0.f, 0.f, 0.f};

    const int r = tid >> 2, ch = tid & 3;
    const bf16* Arow = Wr + (size_t)(mt * 64 + r) * CC + ch * 8;

    for (int kk = 0; kk < 9; ++kk) {
        const int dy = kk / 3 - 1, dx = kk - (kk / 3) * 3 - 1;
        const int ys = y + dy, xs = r + dx;
        const bool ok = (ys >= 0) && (ys < HH) && (xs >= 0) && (xs < WW);
        const bf16* Brow = xT + (size_t)(ys * WW + xs) * CC + ch * 8;
        const bf16* Ak = Arow + (size_t)kk * (512 * CC);
        for (int c0 = 0; c0 < CC; c0 += 32) {
            uint4 av = *(const uint4*)(Ak + c0);
            uint4 bv = make_uint4(0u, 0u, 0u, 0u);
            if (ok) bv = *(const uint4*)(Brow + c0);
            __syncthreads();
            *(uint4*)&Asm[r * 40 + ch * 8] = av;
            *(uint4*)&Bsm[r * 40 + ch * 8] = bv;
            __syncthreads();
            bf16x8v a0 = *(const bf16x8v*)&Asm[(wm + lr) * 40 + q * 8];
            bf16x8v a1 = *(const bf16x8v*)&Asm[(wm + 16 + lr) * 40 + q * 8];
            bf16x8v b0 = *(const bf16x8v*)&Bsm[(wn + lr) * 40 + q * 8];
            bf16x8v b1 = *(const bf16x8v*)&Bsm[(wn + 16 + lr) * 40 + q * 8];
            acc[0][0] = __builtin_amdgcn_mfma_f32_16x16x32_bf16(a0, b0, acc[0][0], 0, 0, 0);
            acc[0][1] = __builtin_amdgcn_mfma_f32_16x16x32_bf16(a0, b1, acc[0][1], 0, 0, 0);
            acc[1][0] = __builtin_amdgcn_mfma_f32_16x16x32_bf16(a1, b0, acc[1][0], 0, 0, 0);
            acc[1][1] = __builtin_amdgcn_mfma_f32_16x16x32_bf16(a1, b1, acc[1][1], 0, 0, 0);
        }
    }

    __syncthreads();
    #pragma unroll
    for (int fm = 0; fm < 2; ++fm)
        #pragma unroll
        for (int fn = 0; fn < 2; ++fn)
            #pragma unroll
            for (int reg = 0; reg < 4; ++reg)
                eb[(wm + fm * 16 + q * 4 + reg) * 72 + (wn + fn * 16 + lr)] = acc[fm][fn][reg];
    __syncthreads();
    {
        const int oc_l = tid >> 3, nch = tid & 7;
        const int oc = mt * 32 + oc_l;
        const float invx = b2f(bnx[oc]) * rsqrtf(b2f(bnx[3 * CC + oc]) + EPSF);
        const float bx   = b2f(bnx[CC + oc]);
        const float mx   = b2f(bnx[2 * CC + oc]);
        const float invy = b2f(bny[oc]) * rsqrtf(b2f(bny[3 * CC + oc]) + EPSF);
        const float by   = b2f(bny[CC + oc]);
        const float my   = b2f(bny[2 * CC + oc]);
        bf16 outv[8];
        #pragma unroll
        for (int j = 0; j < 8; ++j) {
            float gxv = eb[(2 * oc_l) * 72 + nch * 8 + j];
            float gyv = eb[(2 * oc_l + 1) * 72 + nch * 8 + j];
            float gxn = (gxv - mx) * invx + bx;
            float gyn = (gyv - my) * invy + by;
            outv[j] = f2b(sqrtf(gxn * gxn + gyn * gyn));
        }
        *(uint4*)(xf + (size_t)oc * NN + y * WW + nch * 8) = *(const uint4*)outv;
    }
}

// ---------------- f32 path prep: x f32 [256][4096] -> xT_hi + xT_lo bf16 [4096][256] ----------------
__global__ __launch_bounds__(256)
void transpose_split_kernel(const int* __restrict__ dflag,
                            const float* __restrict__ x,
                            bf16* __restrict__ xT_hi, bf16* __restrict__ xT_lo)
{
    if (*dflag != 1) return;
    const int ci0 = blockIdx.x * 64;   // 4
    const int p0  = blockIdx.y * 64;   // 64
    const int t = threadIdx.x;
    const int r = t >> 2, ch = t & 3;

    __shared__ float tile[64][76];

    {
        const float* src = x + (size_t)(ci0 + r) * NN + p0 + ch * 16;
        #pragma unroll
        for (int i = 0; i < 4; ++i) {
            float4 v = *(const float4*)(src + i * 4);
            *(float4*)&tile[r][ch * 16 + i * 4] = v;
        }
    }
    __syncthreads();
    {
        bf16 hi[16], lo[16];
        #pragma unroll
        for (int j = 0; j < 16; ++j) {
            float v = tile[ch * 16 + j][r];
            bf16 h = f2b(v);
            hi[j] = h;
            lo[j] = f2b(v - b2f(h));
        }
        size_t base = (size_t)(p0 + r) * CC + ci0 + ch * 16;
        *(uint4*)(xT_hi + base)     = ((const uint4*)hi)[0];
        *(uint4*)(xT_hi + base + 8) = ((const uint4*)hi)[1];
        *(uint4*)(xT_lo + base)     = ((const uint4*)lo)[0];
        *(uint4*)(xT_lo + base + 8) = ((const uint4*)lo)[1];
    }
}

// ---------------- K1 (f32): Sobel as split-precision implicit-GEMM MFMA ----------------
// v3: hoisted A staging — all 3 dx slices staged per (c0,dy), 18 MFMA per
// barrier pair. Barriers/block: 144 -> 48. LDS 25.9 KB. Same math as v2.
__global__ __launch_bounds__(256)
void sobel_mfma_f32_kernel(const int* __restrict__ dflag,
                           const bf16* __restrict__ xTh,
                           const bf16* __restrict__ xTl,
                           const float* __restrict__ wx,
                           const float* __restrict__ wy,
                           const float* __restrict__ bnx,
                           const float* __restrict__ bny,
                           bf16* __restrict__ xf)
{
    if (*dflag != 1) return;
    const int mt = blockIdx.x;      // 0..15 (32 M-rows each; m = 2*oc + isY, 16 oc/block)
    const int y  = blockIdx.y;      // 0..63
    const int tid = threadIdx.x;
    const int w = tid >> 6, lane = tid & 63;
    const int wm = (w >> 1) * 16, wn = (w & 1) * 32;
    const int lr = lane & 15, q = lane >> 4;

    __shared__ char smem[25920];
    bf16* Ah = (bf16*)smem;          // [3][32][40] (7680 B)
    bf16* Al = Ah + 3840;            // [3][32][40]
    bf16* Bh = Al + 3840;            // [66][40] halo rows 0,65 zero (5280 B)
    bf16* Bl = Bh + 2640;            // [66][40]
    float* eb = (float*)smem;        // [32][72] epilogue reuse (9216 B)

    f32x4v acc[2];
    acc[0] = (f32x4v){0.f, 0.f, 0.f, 0.f};
    acc[1] = (f32x4v){0.f, 0.f, 0.f, 0.f};

    const int r = tid >> 2, ch = tid & 3;     // B staging row (0..63)
    const bool aAct = tid < 128;              // A rows 0..31
    const int o = mt * 16 + (r >> 1);         // valid when aAct
    const float* wbase = aAct ? (((r & 1) ? wy : wx) + (size_t)o * 2304) : wx;

    if (tid < 40) {
        Bh[tid] = f2b(0.f);           Bl[tid] = f2b(0.f);
        Bh[65 * 40 + tid] = f2b(0.f); Bl[65 * 40 + tid] = f2b(0.f);
    }

    for (int c0i = 0; c0i < 8; ++c0i) {
        const int c0 = c0i * 32;
        for (int dy = 0; dy < 3; ++dy) {
            const int ys = y + dy - 1;
            float wv[8][3];
            if (aAct) {
                const float* wb = wbase + (size_t)(c0 + ch * 8) * 9 + dy * 3;
                #pragma unroll
                for (int j = 0; j < 8; ++j)
                    #pragma unroll
                    for (int d = 0; d < 3; ++d)
                        wv[j][d] = wb[j * 9 + d];
            }
            uint4 bh = make_uint4(0u, 0u, 0u, 0u), bl = make_uint4(0u, 0u, 0u, 0u);
            if (ys >= 0 && ys < HH) {
                size_t bidx = (size_t)(ys * WW + r) * CC + c0 + ch * 8;
                bh = *(const uint4*)(xTh + bidx);
                bl = *(const uint4*)(xTl + bidx);
            }
            __syncthreads();                  // prior iteration's frag reads done
            if (aAct) {
                #pragma unroll
                for (int d = 0; d < 3; ++d) {
                    bf16 ah8[8], al8[8];
                    #pragma unroll
                    for (int j = 0; j < 8; ++j) {
                        float v = wv[j][d];
                        bf16 h = f2b(v);
                        ah8[j] = h;
                        al8[j] = f2b(v - b2f(h));
                    }
                    *(uint4*)&Ah[d * 1280 + r * 40 + ch * 8] = *(const uint4*)ah8;
                    *(uint4*)&Al[d * 1280 + r * 40 + ch * 8] = *(const uint4*)al8;
                }
            }
            *(uint4*)&Bh[(r + 1) * 40 + ch * 8] = bh;
            *(uint4*)&Bl[(r + 1) * 40 + ch * 8] = bl;
            __syncthreads();                  // A (3 slices) + B staged
            #pragma unroll
            for (int d = 0; d < 3; ++d) {
                bf16x8v ah0 = *(const bf16x8v*)&Ah[d * 1280 + (wm + lr) * 40 + q * 8];
                bf16x8v al0 = *(const bf16x8v*)&Al[d * 1280 + (wm + lr) * 40 + q * 8];
                const int b0r = wn + lr + d, b1r = wn + 16 + lr + d;
                bf16x8v bh0 = *(const bf16x8v*)&Bh[b0r * 40 + q * 8];
                bf16x8v bh1 = *(const bf16x8v*)&Bh[b1r * 40 + q * 8];
                bf16x8v bl0 = *(const bf16x8v*)&Bl[b0r * 40 + q * 8];
                bf16x8v bl1 = *(const bf16x8v*)&Bl[b1r * 40 + q * 8];
                acc[0] = __builtin_amdgcn_mfma_f32_16x16x32_bf16(ah0, bh0, acc[0], 0, 0, 0);
                acc[0] = __builtin_amdgcn_mfma_f32_16x16x32_bf16(ah0, bl0, acc[0], 0, 0, 0);
                acc[0] = __builtin_amdgcn_mfma_f32_16x16x32_bf16(al0, bh0, acc[0], 0, 0, 0);
                acc[1] = __builtin_amdgcn_mfma_f32_16x16x32_bf16(ah0, bh1, acc[1], 0, 0, 0);
                acc[1] = __builtin_amdgcn_mfma_f32_16x16x32_bf16(ah0, bl1, acc[1], 0, 0, 0);
                acc[1] = __builtin_amdgcn_mfma_f32_16x16x32_bf16(al0, bh1, acc[1], 0, 0, 0);
            }
        }
    }

    __syncthreads();
    #pragma unroll
    for (int fn = 0; fn < 2; ++fn)
        #pragma unroll
        for (int reg = 0; reg < 4; ++reg)
            eb[(wm + q * 4 + reg) * 72 + (wn + fn * 16 + lr)] = acc[fn][reg];
    __syncthreads();
    if (tid < 128) {
        const int oc_l = tid >> 3, nch = tid & 7;
        const int oc = mt * 16 + oc_l;
        const float invx = bnx[oc] * rsqrtf(bnx[3 * CC + oc] + EPSF);
        const float bx   = bnx[CC + oc];
        const float mx   = bnx[2 * CC + oc];
        const float invy = bny[oc] * rsqrtf(bny[3 * CC + oc] + EPSF);
        const float by   = bny[CC + oc];
        const float my   = bny[2 * CC + oc];
        bf16 outv[8];
        #pragma unroll
        for (int j = 0; j < 8; ++j) {
            float gxv = eb[(2 * oc_l) * 72 + nch * 8 + j];
            float gyv = eb[(2 * oc_l + 1) * 72 + nch * 8 + j];
            float gxn = (gxv - mx) * invx + bx;
            float gyn = (gyv - my) * invy + by;
            outv[j] = f2b(sqrtf(gxn * gxn + gyn * gyn));
        }
        *(uint4*)(xf + (size_t)oc * NN + y * WW + nch * 8) = *(const uint4*)outv;
    }
}

// ---------------- K2: 1x1 convs -> MFMA-ready q/k/v operands ----------------
// v3: flat 640-unit all-active grid, plain c-loop (no forced unroll).
template<typename T>
__global__ __launch_bounds__(256)
void qkv_kernel(const int* __restrict__ dflag, int want,
                const T* __restrict__ x1, const T* __restrict__ x2,
                const bf16* __restrict__ xf1, const bf16* __restrict__ xf2,
                const T* __restrict__ q1w, const T* __restrict__ q1b,
                const T* __restrict__ k1w, const T* __restrict__ k1b,
                const T* __restrict__ v1w, const T* __restrict__ v1b,
                const T* __restrict__ q2w, const T* __restrict__ q2b,
                const T* __restrict__ k2w, const T* __restrict__ k2b,
                const T* __restrict__ v2w, const T* __restrict__ v2b,
                bf16* __restrict__ qc1, bf16* __restrict__ kc1, bf16* __restrict__ v1t,
                bf16* __restrict__ qc2, bf16* __restrict__ kc2, bf16* __restrict__ v2t)
{
    if (*dflag != want) return;
    const int unit = blockIdx.x;
    int z, o0, n0;
    if (unit < 128) {
        const int s = unit >> 5;             // 0..3
        const int rem = unit & 31;
        o0 = (rem >> 4) * 16;                // 0 or 16
        n0 = (rem & 15) * 256;
        z = (s == 0) ? 0 : (s == 1) ? 1 : (s == 2) ? 3 : 4;
    } else {
        const int u = unit - 128;            // 0..511
        const int rem = u & 255;
        o0 = (rem >> 4) * 16;                // 0..240
        n0 = (rem & 15) * 256;
        z = (u >> 8) ? 5 : 2;
    }

    const T* Wb; const T* bias;
    const T* Xt = nullptr; const bf16* Xb = nullptr;
    bf16* outQ = nullptr; bf16* outK = nullptr; bf16* outV = nullptr;
    switch (z) {
        case 0:  Wb = q1w; bias = q1b; Xt = x1;  outQ = qc1; break;
        case 1:  Wb = k1w; bias = k1b; Xb = xf2; outK = kc1; break;
        case 2:  Wb = v1w; bias = v1b; Xb = xf2; outV = v1t; break;
        case 3:  Wb = q2w; bias = q2b; Xt = x2;  outQ = qc2; break;
        case 4:  Wb = k2w; bias = k2b; Xb = xf1; outK = kc2; break;
        default: Wb = v2w; bias = v2b; Xb = xf1; outV = v2t; break;
    }
    const int tid = threadIdx.x;

    __shared__ float lw[16 * 256];        // lw[o][c]
    for (int idx = tid; idx < 16 * 256; idx += 256)
        lw[idx] = ldf(Wb, (size_t)o0 * CC + idx);
    __syncthreads();

    const int n = n0 + tid;

    float acc[16];
    #pragma unroll
    for (int o = 0; o < 16; ++o) acc[o] = 0.f;

    const float4* lw4 = (const float4*)lw;
    for (int c4 = 0; c4 < 64; ++c4) {
        float xa[4];
        #pragma unroll
        for (int k = 0; k < 4; ++k) {
            size_t ia = (size_t)(c4 * 4 + k) * NN + n;
            xa[k] = Xt ? ldf(Xt, ia) : b2f(Xb[ia]);
        }
        #pragma unroll
        for (int o = 0; o < 16; ++o) {
            float4 w4 = lw4[o * 64 + c4];
            acc[o] = fmaf(w4.x, xa[0], fmaf(w4.y, xa[1], fmaf(w4.z, xa[2], fmaf(w4.w, xa[3], acc[o]))));
        }
    }
    #pragma unroll
    for (int o = 0; o < 16; ++o) acc[o] += ldf(bias, o0 + o);

    if (outV) {
        #pragma unroll
        for (int o = 0; o < 16; ++o)
            outV[((size_t)(n >> 6) * CC + (o0 + o)) * 64 + (n & 63)] = f2b(acc[o]);
    } else {
        bf16 hi[16], lo[16];
        #pragma unroll
        for (int o = 0; o < 16; ++o) {
            float v = acc[o];
            bf16 h = f2b(v);
            hi[o] = h;
            lo[o] = f2b(v - b2f(h));
        }
        if (outQ) {
            bf16* row = outQ + (size_t)n * 64 + o0;      // hi at [o0, o0+16)
            ((uint4*)row)[0] = ((const uint4*)hi)[0];
            ((uint4*)row)[1] = ((const uint4*)hi)[1];
            bf16* rowl = row + 32;                       // lo at [32+o0, ...)
            ((uint4*)rowl)[0] = ((const uint4*)lo)[0];
            ((uint4*)rowl)[1] = ((const uint4*)lo)[1];
        } else {
            bf16* row = outK + (size_t)n * 96 + o0;
            ((uint4*)row)[0] = ((const uint4*)hi)[0];
            ((uint4*)row)[1] = ((const uint4*)hi)[1];
            bf16* row2 = row + 32;
            ((uint4*)row2)[0] = ((const uint4*)hi)[0];
            ((uint4*)row2)[1] = ((const uint4*)hi)[1];
            bf16* row3 = row + 64;
            ((uint4*)row3)[0] = ((const uint4*)lo)[0];
            ((uint4*)row3)[1] = ((const uint4*)lo)[1];
        }
    }
}

// ---------------- K3: MFMA flash attention (v9: quarter-split QK^T) ----------------
// REVERTED to round-14's measured-best (108 us). Round-15's channel-split
// (v10) regressed to 130 us: occupancy rose 20->35% but the duplicated
// K-staging + QK^T across half-pairs grew total work faster than the extra
// blocks hid latency (conflicts doubled back to 9.4M).
// 512 blocks (att = b>>8, 16-query tile), 256 thr / 4 waves, 2 blk/CU.
// LDS 52.5 KB: Kc [64][128] swz + Vt [256][64] swz + Ph/Pl [16][72].
__device__ __forceinline__ int vswz(int chunk, int row) { return (chunk ^ (row & 7)) * 8; }

template<typename T>
__global__ __launch_bounds__(256)
void attend_mfma_kernel(const int* __restrict__ dflag, int want,
                        const bf16* __restrict__ qc1, const bf16* __restrict__ kc1,
                        const bf16* __restrict__ v1, const T* __restrict__ x1,
                        const T* __restrict__ g1,
                        const bf16* __restrict__ qc2, const bf16* __restrict__ kc2,
                        const bf16* __restrict__ v2, const T* __restrict__ x2,
                        const T* __restrict__ g2,
                        T* __restrict__ out)
{
    if (*dflag != want) return;
    const int att = blockIdx.x >> 8;
    const int i0 = (blockIdx.x & 255) * 16;
    const bf16* qc = att ? qc2 : qc1;
    const bf16* kc = att ? kc2 : kc1;
    const bf16* vt = att ? v2 : v1;
    const T* xq = att ? x2 : x1;
    const T* gp = att ? g2 : g1;
    T* o = out + (size_t)att * CC * NN;

    const int tid = threadIdx.x;
    const int w = tid >> 6, lane = tid & 63;
    const int lr = lane & 15, g = lane >> 4;

    __shared__ __align__(16) bf16 lds[26880];   // 53760 B
    bf16* Kc = lds;                  // [64][128] swizzled (16384 B)
    bf16* Vt = lds + 8192;           // [256][64] swizzled (32768 B)
    bf16* Ph = lds + 24576;          // [16][72]
    bf16* Pl = lds + 25728;          // [16][72]

    // Q fragments: row q = i0+lr, k-chunk g*8 (A-frag layout)
    const bf16* qrow = qc + (size_t)(i0 + lr) * 64 + g * 8;
    bf16x8v qh = *(const bf16x8v*)(qrow);
    bf16x8v ql = *(const bf16x8v*)(qrow + 32);

    float l_r[4];
    #pragma unroll
    for (int r = 0; r < 4; ++r) l_r[r] = 0.f;
    f32x4v oacc[4];
    #pragma unroll
    for (int f = 0; f < 4; ++f) oacc[f] = (f32x4v){0.f, 0.f, 0.f, 0.f};

    for (int jt = 0; jt < 64; ++jt) {
        const int j0 = jt * 64;
        __syncthreads();                      // prior tile's LDS reads done
        // stage K tile: 768 uint4 cooperatively, XOR-swizzled rows
        #pragma unroll
        for (int s = 0; s < 3; ++s) {
            int idx = tid + s * 256;
            int row = idx / 12, cq = idx - row * 12;
            uint4 u = *(const uint4*)(kc + (size_t)(j0 + row) * 96 + cq * 8);
            *(uint4*)&Kc[row * 128 + vswz(cq, row)] = u;
        }
        // stage V tile: contiguous 32 KB block (tile-major), fully coalesced
        {
            const bf16* src = vt + ((size_t)jt * (CC * 64));
            #pragma unroll
            for (int i = 0; i < 8; ++i) {
                const int idx = i * 256 + tid;       // 16B-chunk index in tile
                const int c = idx >> 3, chk = idx & 7;
                *(uint4*)&Vt[c * 64 + vswz(chk, c)] =
                    *(const uint4*)(src + (size_t)idx * 8);
            }
        }
        __syncthreads();                      // Kc + Vt ready

        // ---- QK^T: this wave's key quarter only (keys w*16 + lr) ----
        f32x4v e;
        {
            const bf16* kr = Kc + (w * 16 + lr) * 128;
            bf16x8v b0 = *(const bf16x8v*)(kr + vswz(g, lr));
            bf16x8v b1 = *(const bf16x8v*)(kr + vswz(4 + g, lr));
            bf16x8v b2 = *(const bf16x8v*)(kr + vswz(8 + g, lr));
            f32x4v z = (f32x4v){0.f, 0.f, 0.f, 0.f};
            z = __builtin_amdgcn_mfma_f32_16x16x32_bf16(qh, b0, z, 0, 0, 0);
            z = __builtin_amdgcn_mfma_f32_16x16x32_bf16(ql, b1, z, 0, 0, 0);
            z = __builtin_amdgcn_mfma_f32_16x16x32_bf16(qh, b2, z, 0, 0, 0);
            e = z;
        }
        // ---- weights: p = exp(e), partial l over this wave's quarter ----
        #pragma unroll
        for (int r = 0; r < 4; ++r) {
            float p = __expf(e[r]);
            l_r[r] += p;
            bf16 ph = f2b(p);
            Ph[(g * 4 + r) * 72 + w * 16 + lr] = ph;
            Pl[(g * 4 + r) * 72 + w * 16 + lr] = f2b(p - b2f(ph));
        }
        __syncthreads();                      // P complete (cross-wave)

        // ---- PV ----
        bf16x8v pah[2], pal[2];
        #pragma unroll
        for (int ks = 0; ks < 2; ++ks) {
            pah[ks] = *(const bf16x8v*)&Ph[lr * 72 + ks * 32 + g * 8];
            pal[ks] = *(const bf16x8v*)&Pl[lr * 72 + ks * 32 + g * 8];
        }
        #pragma unroll
        for (int f = 0; f < 4; ++f) {
            const int rowc = w * 64 + f * 16 + lr;
            const bf16* vr = Vt + rowc * 64;
            #pragma unroll
            for (int ks = 0; ks < 2; ++ks) {
                bf16x8v bv = *(const bf16x8v*)(vr + vswz(ks * 4 + g, lr));
                oacc[f] = __builtin_amdgcn_mfma_f32_16x16x32_bf16(pah[ks], bv, oacc[f], 0, 0, 0);
                oacc[f] = __builtin_amdgcn_mfma_f32_16x16x32_bf16(pal[ks], bv, oacc[f], 0, 0, 0);
            }
        }
    }

    // ---- reduce l across the 16-lane group (keys within this wave's quarter) ----
    #pragma unroll
    for (int r = 0; r < 4; ++r)
        #pragma unroll
        for (int msk = 1; msk <= 8; msk <<= 1)
            l_r[r] += __shfl_xor(l_r[r], msk);

    // ---- epilogue: transpose via LDS, combine l partials, residual, store ----
    __syncthreads();
    float* ob = (float*)lds;          // [256][20] (5120 floats)
    float* lp = ob + 5120;            // [4][16] per-wave l partials
    #pragma unroll
    for (int f = 0; f < 4; ++f)
        #pragma unroll
        for (int r = 0; r < 4; ++r)
            ob[(w * 64 + f * 16 + lr) * 20 + g * 4 + r] = oacc[f][r];
    if (lr == 0) {
        #pragma unroll
        for (int r = 0; r < 4; ++r) lp[w * 16 + g * 4 + r] = l_r[r];
    }
    __syncthreads();
    {
        const float gm = ldf(gp, 0);
        const int c = tid;
        const size_t rowo = (size_t)c * NN + i0;
        #pragma unroll
        for (int q = 0; q < 16; ++q) {
            float lq = (lp[q] + lp[16 + q]) + (lp[32 + q] + lp[48 + q]);
            float v = ob[c * 20 + q] / lq;
            float xv = ldf(xq, rowo + q);
            stf(o, rowo + q, fmaf(gm, v, xv));
        }
    }
}

extern "C" void kernel_launch(void* const* d_in, const int* in_sizes, int n_in,
                              void* d_out, int out_size, void* d_ws, size_t ws_size,
                              hipStream_t stream) {
    // workspace: 256B flag + xf1(2M) xf2(2M) + union(6.5M):
    //   sobel phase : xT/xTh(2M) Wr|xTl(2.25M/2M)
    //   post-sobel  : v1t(2M) v2t(2M) qc1(512K) kc1(768K) qc2(512K) kc2(768K)
    // total 11,010,304 B (prior session proved ws_size >= 11 MB).
    if (ws_size < (size_t)11010304) return;

    int* dflag = (int*)d_ws;
    char* base = (char*)d_ws + 256;
    bf16* xf1 = (bf16*)base;               // 2 MB
    bf16* xf2 = xf1 + 1048576;             // 2 MB
    char* ubase = (char*)(xf2 + 1048576);  // 6.5 MB union region
    bf16* xTb = (bf16*)ubase;                          // bf16 sobel
    bf16* Wrb = (bf16*)(ubase + 2 * 1024 * 1024);
    bf16* xTh = (bf16*)ubase;                          // f32 sobel
    bf16* xTl = (bf16*)(ubase + 2 * 1024 * 1024);
    bf16* v1t = (bf16*)ubase;              // [64][256][64] bf16 tile-major, 2 MB
    bf16* v2t = v1t + 1048576;             // 2 MB
    bf16* qc1 = v2t + 1048576;             // [4096][64], 512 KB
    bf16* kc1 = qc1 + 262144;              // [4096][96], 768 KB
    bf16* qc2 = kc1 + 393216;              // 512 KB
    bf16* kc2 = qc2 + 262144;              // 768 KB

    detect_kernel<<<dim3(1), 256, 0, stream>>>((const unsigned short*)d_in[0], dflag);

    // ---- bf16 pipeline (want=0) ----
    {
        typedef bf16 T;
        transpose_kernel<<<dim3(4, 64), 256, 0, stream>>>(dflag, (const T*)d_in[0], xTb);
        packw_kernel<<<dim3(1152), 256, 0, stream>>>(dflag, (const T*)d_in[2], (const T*)d_in[3], Wrb);
        sobel_mfma_kernel<<<dim3(8, 64), 256, 0, stream>>>(dflag, xTb, Wrb,
            (const T*)d_in[4], (const T*)d_in[5], xf1);
        transpose_kernel<<<dim3(4, 64), 256, 0, stream>>>(dflag, (const T*)d_in[1], xTb);
        packw_kernel<<<dim3(1152), 256, 0, stream>>>(dflag, (const T*)d_in[6], (const T*)d_in[7], Wrb);
        sobel_mfma_kernel<<<dim3(8, 64), 256, 0, stream>>>(dflag, xTb, Wrb,
            (const T*)d_in[8], (const T*)d_in[9], xf2);
        qkv_kernel<T><<<dim3(640), 256, 0, stream>>>(dflag, 0,
            (const T*)d_in[0], (const T*)d_in[1], xf1, xf2,
            (const T*)d_in[10], (const T*)d_in[11], (const T*)d_in[12], (const T*)d_in[13],
            (const T*)d_in[14], (const T*)d_in[15], (const T*)d_in[16], (const T*)d_in[17],
            (const T*)d_in[18], (const T*)d_in[19], (const T*)d_in[20], (const T*)d_in[21],
            qc1, kc1, v1t, qc2, kc2, v2t);
        attend_mfma_kernel<T><<<dim3(512), 256, 0, stream>>>(dflag, 0,
            qc1, kc1, v1t, (const T*)d_in[0], (const T*)d_in[22],
            qc2, kc2, v2t, (const T*)d_in[1], (const T*)d_in[23],
            (T*)d_out);
    }
    // ---- f32 pipeline (want=1) ----
    {
        typedef float T;
        transpose_split_kernel<<<dim3(4, 64), 256, 0, stream>>>(dflag, (const T*)d_in[0], xTh, xTl);
        sobel_mfma_f32_kernel<<<dim3(16, 64), 256, 0, stream>>>(dflag, xTh, xTl,
            (const T*)d_in[2], (const T*)d_in[3], (const T*)d_in[4], (const T*)d_in[5], xf1);
        transpose_split_kernel<<<dim3(4, 64), 256, 0, stream>>>(dflag, (const T*)d_in[1], xTh, xTl);
        sobel_mfma_f32_kernel<<<dim3(16, 64), 256, 0, stream>>>(dflag, xTh, xTl,
            (const T*)d_in[6], (const T*)d_in[7], (const T*)d_in[8], (const T*)d_in[9], xf2);
        qkv_kernel<T><<<dim3(640), 256, 0, stream>>>(dflag, 1,
            (const T*)d_in[0], (const T*)d_in[1], xf1, xf2,
            (const T*)d_in[10], (const T*)d_in[11], (const T*)d_in[12], (const T*)d_in[13],
            (const T*)d_in[14], (const T*)d_in[15], (const T*)d_in[16], (const T*)d_in[17],
            (const T*)d_in[18], (const T*)d_in[19], (const T*)d_in[20], (const T*)d_in[21],
            qc1, kc1, v1t, qc2, kc2, v2t);
        attend_mfma_kernel<T><<<dim3(512), 256, 0, stream>>>(dflag, 1,
            qc1, kc1, v1t, (const T*)d_in[0], (const T*)d_in[22],
            qc2, kc2, v2t, (const T*)d_in[1], (const T*)d_in[23],
            (T*)d_out);
    }
}